// Round 10
// baseline (175.364 us; speedup 1.0000x reference)
//
#include <hip/hip_runtime.h>
#include <hip/hip_bf16.h>
#include <cstdint>
#include <cstddef>

#define N_NODES 50000
#define N_EDGES 800000
#define N_POS   200000
#define N_NEG   200000
#define DIM     128
#define NEG_SLOPE 0.2f

#define BUCK_SHIFT 5
#define BUCK_NODES 32                        // nodes per bucket
#define NBUCK 1563                           // ceil(50000/32)
#define SLABCAP 768                          // edges: mean 512 +11 sigma
#define PSLABCAP 384                         // pairs: mean 256 +8 sigma
#define NB_BIN 391                           // edge-bin blocks (2048 edges each)
#define NB_PBIN 196                          // pair-bin blocks (98 pos + 98 neg)
#define NB_GEMM 782                          // ceil(50000/64)
#define N_EDGE4 200000                       // N_EDGES/4
#define N_PAIR4 50000                        // N_POS/4 == N_NEG/4

typedef _Float16 half8 __attribute__((ext_vector_type(8)));
typedef float    floatx4 __attribute__((ext_vector_type(4)));

// ---------------------------------------------------------------------------
// K0: prep.  Zero edge+pair cursors + build swizzled fp16 W^T in global ws.
// ---------------------------------------------------------------------------
__global__ __launch_bounds__(256) void prep_kernel(
    const float* __restrict__ W, _Float16* __restrict__ wt_g,
    int* __restrict__ cursors)
{
  const int tid = threadIdx.x;
  for (int i = blockIdx.x * 256 + tid; i < 2 * NBUCK; i += 4 * 256)
    cursors[i] = 0;
  const int k = blockIdx.x * 32 + (tid >> 3);
  const int n0 = (tid & 7) * 16;
#pragma unroll
  for (int j = 0; j < 16; j += 4) {
    const float4 v = *(const float4*)&W[(size_t)k * DIM + n0 + j];
    const float vv[4] = {v.x, v.y, v.z, v.w};
#pragma unroll
    for (int u = 0; u < 4; ++u) {
      const int nn = n0 + j + u;
      wt_g[nn * 128 + ((((k >> 3) ^ (nn & 15)) << 3) | (k & 7))] = (_Float16)vv[u];
    }
  }
}

// ---------------------------------------------------------------------------
// K1: fused gemm + edge-bin + pair-bin.
//   blocks [0, 391):        bin edges by dst bucket  (record (src<<5)|dstloc)
//   blocks [391, 587):      bin score pairs by a-node bucket
//                           (record uint2{(b<<5)|a_loc, pair_idx})
//   blocks [587, 1369):     feat = x @ W via MFMA fp16 + fused el/er
// All three are independent; bin paths are latency-bound and co-schedule
// with the MFMA-bound gemm blocks.
// ---------------------------------------------------------------------------
__global__ __launch_bounds__(256) void fused_gemm_bin(
    const float* __restrict__ x, const _Float16* __restrict__ wt_g,
    const float* __restrict__ attn_l, const float* __restrict__ attn_r,
    const int4* __restrict__ src4, const int4* __restrict__ dst4,
    const int4* __restrict__ pos_src4, const int4* __restrict__ pos_dst4,
    const int4* __restrict__ neg_src4, const int4* __restrict__ neg_dst4,
    half8* __restrict__ feat16, float* __restrict__ el, float* __restrict__ er,
    unsigned int* __restrict__ slab, uint2* __restrict__ pslab,
    int* __restrict__ cursors, int n)
{
  __shared__ char smem[49152];
  const int tid = threadIdx.x;

  if (blockIdx.x < NB_BIN) {
    // ---------------- edge-bin path: 2048 edges, 8 per thread --------------
    int* hist   = (int*)smem;
    int* base_s = hist + NBUCK;
    int* cur    = base_s + NBUCK;
    int* slab_cursor = cursors;
    const int i4base = blockIdx.x * 512;
    const int i40 = i4base + tid;
    const int i41 = i4base + 256 + tid;
    const bool v0 = i40 < N_EDGE4;
    const bool v1 = i41 < N_EDGE4;

    for (int i = tid; i < NBUCK; i += 256) { hist[i] = 0; cur[i] = 0; }
    int4 d0 = v0 ? dst4[i40] : make_int4(0, 0, 0, 0);
    int4 d1 = v1 ? dst4[i41] : make_int4(0, 0, 0, 0);
    __syncthreads();

    if (v0) {
      atomicAdd(&hist[d0.x >> BUCK_SHIFT], 1);
      atomicAdd(&hist[d0.y >> BUCK_SHIFT], 1);
      atomicAdd(&hist[d0.z >> BUCK_SHIFT], 1);
      atomicAdd(&hist[d0.w >> BUCK_SHIFT], 1);
    }
    if (v1) {
      atomicAdd(&hist[d1.x >> BUCK_SHIFT], 1);
      atomicAdd(&hist[d1.y >> BUCK_SHIFT], 1);
      atomicAdd(&hist[d1.z >> BUCK_SHIFT], 1);
      atomicAdd(&hist[d1.w >> BUCK_SHIFT], 1);
    }
    int4 s0 = v0 ? src4[i40] : make_int4(0, 0, 0, 0);
    int4 s1 = v1 ? src4[i41] : make_int4(0, 0, 0, 0);
    __syncthreads();

    for (int i = tid; i < NBUCK; i += 256) {
      const int h = hist[i];
      base_s[i] = h ? atomicAdd(&slab_cursor[i], h) : 0;
    }
    __syncthreads();

    int dd[8] = {d0.x, d0.y, d0.z, d0.w, d1.x, d1.y, d1.z, d1.w};
    int ss[8] = {s0.x, s0.y, s0.z, s0.w, s1.x, s1.y, s1.z, s1.w};
#pragma unroll
    for (int u = 0; u < 8; ++u) {
      if (u < 4 ? v0 : v1) {
        const int d = dd[u];
        const int bk = d >> BUCK_SHIFT;
        const int p = atomicAdd(&cur[bk], 1);
        int idx = base_s[bk] + p;
        if (idx >= SLABCAP) idx = SLABCAP - 1;   // statistically never
        slab[(size_t)bk * SLABCAP + idx] =
            ((unsigned int)ss[u] << BUCK_SHIFT) | (unsigned int)(d & (BUCK_NODES - 1));
      }
    }
    return;
  }

  if (blockIdx.x < NB_BIN + NB_PBIN) {
    // ---------------- pair-bin path: 2048 pairs, 8 per thread --------------
    int* hist   = (int*)smem;
    int* base_s = hist + NBUCK;
    int* cur    = base_s + NBUCK;
    int* pcursor = cursors + NBUCK;
    const int pb = blockIdx.x - NB_BIN;
    const bool neg = pb >= 98;
    const int lb = neg ? pb - 98 : pb;
    const int4* a4 = neg ? neg_src4 : pos_src4;
    const int4* b4 = neg ? neg_dst4 : pos_dst4;
    const int idx0 = neg ? N_POS : 0;
    const int i4base = lb * 512;
    const int i40 = i4base + tid;
    const int i41 = i4base + 256 + tid;
    const bool v0 = i40 < N_PAIR4;
    const bool v1 = i41 < N_PAIR4;

    for (int i = tid; i < NBUCK; i += 256) { hist[i] = 0; cur[i] = 0; }
    int4 a0 = v0 ? a4[i40] : make_int4(0, 0, 0, 0);
    int4 a1 = v1 ? a4[i41] : make_int4(0, 0, 0, 0);
    __syncthreads();

    if (v0) {
      atomicAdd(&hist[a0.x >> BUCK_SHIFT], 1);
      atomicAdd(&hist[a0.y >> BUCK_SHIFT], 1);
      atomicAdd(&hist[a0.z >> BUCK_SHIFT], 1);
      atomicAdd(&hist[a0.w >> BUCK_SHIFT], 1);
    }
    if (v1) {
      atomicAdd(&hist[a1.x >> BUCK_SHIFT], 1);
      atomicAdd(&hist[a1.y >> BUCK_SHIFT], 1);
      atomicAdd(&hist[a1.z >> BUCK_SHIFT], 1);
      atomicAdd(&hist[a1.w >> BUCK_SHIFT], 1);
    }
    int4 b0 = v0 ? b4[i40] : make_int4(0, 0, 0, 0);
    int4 b1 = v1 ? b4[i41] : make_int4(0, 0, 0, 0);
    __syncthreads();

    for (int i = tid; i < NBUCK; i += 256) {
      const int h = hist[i];
      base_s[i] = h ? atomicAdd(&pcursor[i], h) : 0;
    }
    __syncthreads();

    int aa[8] = {a0.x, a0.y, a0.z, a0.w, a1.x, a1.y, a1.z, a1.w};
    int bb[8] = {b0.x, b0.y, b0.z, b0.w, b1.x, b1.y, b1.z, b1.w};
#pragma unroll
    for (int u = 0; u < 8; ++u) {
      if (u < 4 ? v0 : v1) {
        const int a = aa[u];
        const int bk = a >> BUCK_SHIFT;
        const int p = atomicAdd(&cur[bk], 1);
        int idx = base_s[bk] + p;
        if (idx >= PSLABCAP) idx = PSLABCAP - 1; // statistically never
        const int pidx = idx0 + ((u < 4) ? (i40 * 4 + u) : (i41 * 4 + (u - 4)));
        pslab[(size_t)bk * PSLABCAP + idx] =
            make_uint2(((unsigned int)bb[u] << BUCK_SHIFT) |
                       (unsigned int)(a & (BUCK_NODES - 1)),
                       (unsigned int)pidx);
      }
    }
    return;
  }

  // ---------------- gemm path: 64 rows x 128 cols, 4 waves x 16 rows -------
  _Float16* xt = (_Float16*)smem;            // 16 KB, swizzled [row][k]
  _Float16* wt = (_Float16*)(smem + 16384);  // 32 KB, swizzled [n][k]
  const int row0 = (blockIdx.x - NB_BIN - NB_PBIN) * 64;
  const int lane = tid & 63;
  const int wv = tid >> 6;
  const int ql = lane & 15;
  const int quad = lane >> 4;

  {
    const half8* s = (const half8*)wt_g;
    half8* d = (half8*)wt;
#pragma unroll
    for (int i = 0; i < 8; ++i) d[tid + i * 256] = s[tid + i * 256];
  }
  {
    const int r = tid >> 2;
    const int grow = row0 + r;
    const int c0 = (tid & 3) * 32;
#pragma unroll
    for (int cc = 0; cc < 32; cc += 8) {
      const int c = c0 + cc;
      float4 v0 = make_float4(0.f, 0.f, 0.f, 0.f);
      float4 v1 = make_float4(0.f, 0.f, 0.f, 0.f);
      if (grow < n) {
        const float* sp = &x[(size_t)grow * DIM + c];
        v0 = *(const float4*)(sp);
        v1 = *(const float4*)(sp + 4);
      }
      half8 h;
      h[0] = (_Float16)v0.x; h[1] = (_Float16)v0.y;
      h[2] = (_Float16)v0.z; h[3] = (_Float16)v0.w;
      h[4] = (_Float16)v1.x; h[5] = (_Float16)v1.y;
      h[6] = (_Float16)v1.z; h[7] = (_Float16)v1.w;
      const int chunk = c >> 3;
      *(half8*)&xt[r * 128 + ((chunk ^ (r & 15)) << 3)] = h;
    }
  }
  __syncthreads();

  floatx4 acc[8];
#pragma unroll
  for (int t = 0; t < 8; ++t) acc[t] = (floatx4){0.f, 0.f, 0.f, 0.f};

  const int arow = wv * 16 + ql;
  half8 af[4];
#pragma unroll
  for (int s = 0; s < 4; ++s) {
    const int chunk = s * 4 + quad;
    af[s] = *(half8*)&xt[arow * 128 + ((chunk ^ ql) << 3)];
  }
#pragma unroll
  for (int t = 0; t < 8; ++t) {
    const int brow = t * 16 + ql;
#pragma unroll
    for (int s = 0; s < 4; ++s) {
      const int chunk = s * 4 + quad;
      const half8 bf = *(half8*)&wt[brow * 128 + ((chunk ^ ql) << 3)];
      acc[t] = __builtin_amdgcn_mfma_f32_16x16x32_f16(af[s], bf, acc[t], 0, 0, 0);
    }
  }

  {
    float al8[8], ar8[8];
#pragma unroll
    for (int t = 0; t < 8; ++t) {
      al8[t] = attn_l[t * 16 + ql];
      ar8[t] = attn_r[t * 16 + ql];
    }
    float pl[4] = {0.f, 0.f, 0.f, 0.f};
    float pr[4] = {0.f, 0.f, 0.f, 0.f};
#pragma unroll
    for (int t = 0; t < 8; ++t)
#pragma unroll
      for (int r = 0; r < 4; ++r) {
        pl[r] = fmaf(acc[t][r], al8[t], pl[r]);
        pr[r] = fmaf(acc[t][r], ar8[t], pr[r]);
      }
#pragma unroll
    for (int o = 1; o < 16; o <<= 1)
#pragma unroll
      for (int r = 0; r < 4; ++r) {
        pl[r] += __shfl_xor(pl[r], o, 64);
        pr[r] += __shfl_xor(pr[r], o, 64);
      }
    if (ql == 0) {
#pragma unroll
      for (int r = 0; r < 4; ++r) {
        const int grow = row0 + wv * 16 + quad * 4 + r;
        if (grow < n) { el[grow] = pl[r]; er[grow] = pr[r]; }
      }
    }
  }

#pragma unroll
  for (int t = 0; t < 8; ++t)
#pragma unroll
    for (int r = 0; r < 4; ++r)
      xt[(wv * 16 + quad * 4 + r) * 128 + t * 16 + ql] = (_Float16)acc[t][r];
  __syncthreads();
  {
    const int r = tid >> 2;
    const int grow = row0 + r;
    if (grow < n) {
      const int c0 = (tid & 3) * 32;
#pragma unroll
      for (int cc = 0; cc < 32; cc += 8) {
        const half8 h = *(half8*)&xt[r * 128 + c0 + cc];
        feat16[(size_t)grow * 16 + ((c0 + cc) >> 3)] = h;
      }
    }
  }
}

// ---------------------------------------------------------------------------
// K2: aggregation.  One block per 32-node bucket (1563 blocks).  LDS sort by
// exact dst, then 16-lane quarter-waves own 2 nodes each; single fused pass
// (no max-subtraction), w computed 16-wide then shfl-broadcast, gather x4.
// ---------------------------------------------------------------------------
__global__ __launch_bounds__(256) void aggregate_kernel(
    const half8* __restrict__ feat16, const float* __restrict__ el,
    const float* __restrict__ er,
    const unsigned int* __restrict__ slab, const int* __restrict__ cursors,
    const float* __restrict__ bias, half8* __restrict__ h16)
{
  __shared__ unsigned int csr[SLABCAP];
  __shared__ int cnt_l[BUCK_NODES];
  __shared__ int start_l[BUCK_NODES];
  __shared__ int cur_l[BUCK_NODES];
  const int b = blockIdx.x;
  const int tid = threadIdx.x;
  const int cnt = min(cursors[b], SLABCAP);
  const unsigned int* sb = slab + (size_t)b * SLABCAP;
  const int node0 = b << BUCK_SHIFT;

  if (tid < BUCK_NODES) cnt_l[tid] = 0;
  __syncthreads();
  for (int i = tid; i < cnt; i += 256)
    atomicAdd(&cnt_l[sb[i] & (BUCK_NODES - 1)], 1);
  __syncthreads();
  if (tid < 64) {
    const int v = (tid < BUCK_NODES) ? cnt_l[tid] : 0;
    int inc = v;
#pragma unroll
    for (int d = 1; d < 32; d <<= 1) {
      const int t = __shfl_up(inc, d, 64);
      if (tid >= d) inc += t;
    }
    if (tid < BUCK_NODES) { start_l[tid] = inc - v; cur_l[tid] = 0; }
  }
  __syncthreads();
  for (int i = tid; i < cnt; i += 256) {
    const unsigned int r = sb[i];
    const int p = atomicAdd(&cur_l[r & (BUCK_NODES - 1)], 1);
    csr[start_l[r & (BUCK_NODES - 1)] + p] = r;
  }
  __syncthreads();

  const int lane = tid & 63;
  const int ql = lane & 15;
  const int qb = lane & 48;
  const int qid = (tid >> 6) * 4 + (lane >> 4);
  const float4 b0 = *(const float4*)&bias[ql * 8];
  const float4 b1 = *(const float4*)&bias[ql * 8 + 4];
  const float bb[8] = {b0.x, b0.y, b0.z, b0.w, b1.x, b1.y, b1.z, b1.w};

  for (int nl = qid; nl < BUCK_NODES; nl += 16) {
    const int node = node0 + nl;
    if (node >= N_NODES) break;
    const int beg = start_l[nl];
    const int c = cnt_l[nl];
    const float ern = er[node];

    float sp = 0.f;
    float acc[8];
#pragma unroll
    for (int k = 0; k < 8; ++k) acc[k] = 0.f;

    for (int t0 = 0; t0 < c; t0 += 16) {
      const int t = t0 + ql;
      const unsigned int r = csr[beg + ((t < c) ? t : (c - 1))];
      const int sid = (int)(r >> BUCK_SHIFT);
      float w = 0.f;
      if (t < c) {
        const float v = el[sid] + ern;
        const float e = (v > 0.f) ? v : NEG_SLOPE * v;
        w = __expf(e);
      }
      sp += w;
      const int nb = min(16, c - t0);
      int j = 0;
      for (; j + 4 <= nb; j += 4) {
        float wv[4]; int sv[4]; half8 fv[4];
#pragma unroll
        for (int u = 0; u < 4; ++u) {
          wv[u] = __shfl(w, qb + j + u, 64);
          sv[u] = __shfl(sid, qb + j + u, 64);
        }
#pragma unroll
        for (int u = 0; u < 4; ++u) fv[u] = feat16[(size_t)sv[u] * 16 + ql];
#pragma unroll
        for (int u = 0; u < 4; ++u)
#pragma unroll
          for (int k = 0; k < 8; ++k)
            acc[k] = fmaf(wv[u], (float)fv[u][k], acc[k]);
      }
      for (; j < nb; ++j) {
        const float wj = __shfl(w, qb + j, 64);
        const int sj = __shfl(sid, qb + j, 64);
        const half8 f = feat16[(size_t)sj * 16 + ql];
#pragma unroll
        for (int k = 0; k < 8; ++k) acc[k] = fmaf(wj, (float)f[k], acc[k]);
      }
    }

#pragma unroll
    for (int o = 1; o < 16; o <<= 1) sp += __shfl_xor(sp, o, 64);

    const float inv = (c > 0) ? 1.f / sp : 0.f;
    half8 o;
#pragma unroll
    for (int k = 0; k < 8; ++k)
      o[k] = (_Float16)fmaxf(acc[k] * inv + bb[k], 0.f);
    h16[(size_t)node * 16 + ql] = o;
  }
}

// ---------------------------------------------------------------------------
// K3: bucket-tiled scores.  One block per 32-node a-bucket: stage the 32
// a-rows in LDS (8 KB, coalesced), then per pair gather only h[b] (256 B
// quarter-wave load, 4 pairs in flight) and dot against the LDS a-row.
// ---------------------------------------------------------------------------
__global__ __launch_bounds__(256) void score_kernel(
    const half8* __restrict__ h16, const uint2* __restrict__ pslab,
    const int* __restrict__ cursors, float* __restrict__ out)
{
  __shared__ _Float16 arow[BUCK_NODES * 128];   // 8 KB
  const int b = blockIdx.x;
  const int tid = threadIdx.x;
  const int node0 = b << BUCK_SHIFT;

  {
    const int r = tid >> 3;            // 0..31
    const int c = (tid & 7) * 2;       // half8 chunk
    const int node = node0 + r;
    half8 v0 = {0, 0, 0, 0, 0, 0, 0, 0};
    half8 v1 = v0;
    if (node < N_NODES) {
      v0 = h16[(size_t)node * 16 + c];
      v1 = h16[(size_t)node * 16 + c + 1];
    }
    *(half8*)&arow[r * 128 + c * 8] = v0;
    *(half8*)&arow[r * 128 + c * 8 + 8] = v1;
  }
  const int cnt = min(cursors[NBUCK + b], PSLABCAP);
  const uint2* sb = pslab + (size_t)b * PSLABCAP;
  __syncthreads();

  const int lane = tid & 63;
  const int ql = lane & 15;
  const int qid = (tid >> 6) * 4 + (lane >> 4);  // 0..15

  int i = qid;
  for (; i + 48 < cnt; i += 64) {
    uint2 r[4];
    half8 hb[4], ha[4];
#pragma unroll
    for (int u = 0; u < 4; ++u) r[u] = sb[i + u * 16];
#pragma unroll
    for (int u = 0; u < 4; ++u)
      hb[u] = h16[(size_t)(r[u].x >> BUCK_SHIFT) * 16 + ql];
#pragma unroll
    for (int u = 0; u < 4; ++u)
      ha[u] = *(half8*)&arow[(r[u].x & (BUCK_NODES - 1)) * 128 + ql * 8];
#pragma unroll
    for (int u = 0; u < 4; ++u) {
      float s = 0.f;
#pragma unroll
      for (int k = 0; k < 8; ++k)
        s = fmaf((float)ha[u][k], (float)hb[u][k], s);
#pragma unroll
      for (int o = 1; o < 16; o <<= 1) s += __shfl_xor(s, o, 64);
      if (ql == 0) out[r[u].y] = s;
    }
  }
  for (; i < cnt; i += 16) {
    const uint2 r = sb[i];
    const half8 hb = h16[(size_t)(r.x >> BUCK_SHIFT) * 16 + ql];
    const half8 ha = *(half8*)&arow[(r.x & (BUCK_NODES - 1)) * 128 + ql * 8];
    float s = 0.f;
#pragma unroll
    for (int k = 0; k < 8; ++k)
      s = fmaf((float)ha[k], (float)hb[k], s);
#pragma unroll
    for (int o = 1; o < 16; o <<= 1) s += __shfl_xor(s, o, 64);
    if (ql == 0) out[r.y] = s;
  }
}

// ---------------------------------------------------------------------------
extern "C" void kernel_launch(void* const* d_in, const int* in_sizes, int n_in,
                              void* d_out, int out_size, void* d_ws, size_t ws_size,
                              hipStream_t stream) {
  const float* x      = (const float*)d_in[0];
  const float* W      = (const float*)d_in[1];
  const float* attn_l = (const float*)d_in[2];
  const float* attn_r = (const float*)d_in[3];
  const float* bias   = (const float*)d_in[4];
  const int* src      = (const int*)d_in[5];
  const int* dst      = (const int*)d_in[6];
  const int* pos_src  = (const int*)d_in[7];
  const int* pos_dst  = (const int*)d_in[8];
  const int* neg_src  = (const int*)d_in[9];
  const int* neg_dst  = (const int*)d_in[10];
  float* out = (float*)d_out;

  char* ws = (char*)d_ws;
  const size_t F16B   = (size_t)N_NODES * DIM * sizeof(_Float16);       // 12.8 MB
  const size_t SLAB_B = (size_t)NBUCK * SLABCAP * sizeof(unsigned int); // 4.8 MB
  const size_t PSLB_B = (size_t)NBUCK * PSLABCAP * sizeof(uint2);       // 4.8 MB
  half8* feat16      = (half8*)(ws);
  half8* h16         = (half8*)(ws + F16B);
  float* el          = (float*)(ws + 2 * F16B);
  float* er          = (float*)(ws + 2 * F16B + 200000);
  int*   cursors     = (int*)  (ws + 2 * F16B + 400000);       // 2*NBUCK ints
  unsigned int* slab = (unsigned int*)(ws + 2 * F16B + 416384);
  uint2* pslab       = (uint2*)(ws + 2 * F16B + 416384 + SLAB_B);
  _Float16* wt_g     = (_Float16*)(ws + 2 * F16B + 416384 + SLAB_B + PSLB_B);

  prep_kernel<<<4, 256, 0, stream>>>(W, wt_g, cursors);
  fused_gemm_bin<<<NB_BIN + NB_PBIN + NB_GEMM, 256, 0, stream>>>(
      x, wt_g, attn_l, attn_r,
      (const int4*)src, (const int4*)dst,
      (const int4*)pos_src, (const int4*)pos_dst,
      (const int4*)neg_src, (const int4*)neg_dst,
      feat16, el, er, slab, pslab, cursors, N_NODES);
  aggregate_kernel<<<NBUCK, 256, 0, stream>>>(
      feat16, el, er, slab, cursors, bias, h16);
  score_kernel<<<NBUCK, 256, 0, stream>>>(h16, pslab, cursors, out);
}

// Round 11
// 166.154 us; speedup vs baseline: 1.0554x; 1.0554x over previous
//
#include <hip/hip_runtime.h>
#include <hip/hip_bf16.h>
#include <hip/hip_fp8.h>
#include <cstdint>
#include <cstddef>

#define N_NODES 50000
#define N_EDGES 800000
#define N_POS   200000
#define N_NEG   200000
#define DIM     128
#define NEG_SLOPE 0.2f

#define BUCK_SHIFT 5
#define BUCK_NODES 32                        // nodes per bucket
#define NBUCK 1563                           // ceil(50000/32)
#define SLABCAP 768                          // mean 512, sigma 22.6 -> +11 sigma
#define NB_BIN 391                           // ceil(800000/2048)
#define NB_GEMM 782                          // ceil(50000/64)
#define N_EDGE4 200000                       // N_EDGES/4

typedef _Float16 half8 __attribute__((ext_vector_type(8)));
typedef float    floatx4 __attribute__((ext_vector_type(4)));

__device__ __forceinline__ float fp8_to_f(unsigned char b) {
  __hip_fp8_e4m3 q; q.__x = (__hip_fp8_storage_t)b; return (float)q;
}
__device__ __forceinline__ unsigned char f_to_fp8(float v) {
  __hip_fp8_e4m3 q(v); return (unsigned char)q.__x;
}

// ---------------------------------------------------------------------------
// K0: prep.  Zero slab cursors + build swizzled fp16 W^T in global ws.
// ---------------------------------------------------------------------------
__global__ __launch_bounds__(256) void prep_kernel(
    const float* __restrict__ W, _Float16* __restrict__ wt_g,
    int* __restrict__ cursors)
{
  const int tid = threadIdx.x;
  for (int i = blockIdx.x * 256 + tid; i < NBUCK; i += 4 * 256)
    cursors[i] = 0;
  const int k = blockIdx.x * 32 + (tid >> 3);
  const int n0 = (tid & 7) * 16;
#pragma unroll
  for (int j = 0; j < 16; j += 4) {
    const float4 v = *(const float4*)&W[(size_t)k * DIM + n0 + j];
    const float vv[4] = {v.x, v.y, v.z, v.w};
#pragma unroll
    for (int u = 0; u < 4; ++u) {
      const int nn = n0 + j + u;
      wt_g[nn * 128 + ((((k >> 3) ^ (nn & 15)) << 3) | (k & 7))] = (_Float16)vv[u];
    }
  }
}

// ---------------------------------------------------------------------------
// K1: fused gemm + edge-bin.  Blocks [0, NB_GEMM) = MFMA gemm (long pole,
// launched first); blocks [NB_GEMM, NB_GEMM+NB_BIN) = latency-bound edge bin
// that backfills the CUs.
// ---------------------------------------------------------------------------
__global__ __launch_bounds__(256) void fused_gemm_bin(
    const float* __restrict__ x, const _Float16* __restrict__ wt_g,
    const float* __restrict__ attn_l, const float* __restrict__ attn_r,
    const int4* __restrict__ src4, const int4* __restrict__ dst4,
    half8* __restrict__ feat16, float* __restrict__ el, float* __restrict__ er,
    unsigned int* __restrict__ slab, int* __restrict__ cursors, int n)
{
  __shared__ char smem[49152];
  const int tid = threadIdx.x;

  if (blockIdx.x >= NB_GEMM) {
    // ---------------- edge-bin path: 2048 edges, 8 per thread --------------
    int* hist   = (int*)smem;
    int* base_s = hist + NBUCK;
    int* cur    = base_s + NBUCK;
    const int i4base = (blockIdx.x - NB_GEMM) * 512;
    const int i40 = i4base + tid;
    const int i41 = i4base + 256 + tid;
    const bool v0 = i40 < N_EDGE4;
    const bool v1 = i41 < N_EDGE4;

    for (int i = tid; i < NBUCK; i += 256) { hist[i] = 0; cur[i] = 0; }
    int4 d0 = v0 ? dst4[i40] : make_int4(0, 0, 0, 0);
    int4 d1 = v1 ? dst4[i41] : make_int4(0, 0, 0, 0);
    __syncthreads();

    if (v0) {
      atomicAdd(&hist[d0.x >> BUCK_SHIFT], 1);
      atomicAdd(&hist[d0.y >> BUCK_SHIFT], 1);
      atomicAdd(&hist[d0.z >> BUCK_SHIFT], 1);
      atomicAdd(&hist[d0.w >> BUCK_SHIFT], 1);
    }
    if (v1) {
      atomicAdd(&hist[d1.x >> BUCK_SHIFT], 1);
      atomicAdd(&hist[d1.y >> BUCK_SHIFT], 1);
      atomicAdd(&hist[d1.z >> BUCK_SHIFT], 1);
      atomicAdd(&hist[d1.w >> BUCK_SHIFT], 1);
    }
    int4 s0 = v0 ? src4[i40] : make_int4(0, 0, 0, 0);
    int4 s1 = v1 ? src4[i41] : make_int4(0, 0, 0, 0);
    __syncthreads();

    for (int i = tid; i < NBUCK; i += 256) {
      const int h = hist[i];
      base_s[i] = h ? atomicAdd(&cursors[i], h) : 0;
    }
    __syncthreads();

    int dd[8] = {d0.x, d0.y, d0.z, d0.w, d1.x, d1.y, d1.z, d1.w};
    int ss[8] = {s0.x, s0.y, s0.z, s0.w, s1.x, s1.y, s1.z, s1.w};
#pragma unroll
    for (int u = 0; u < 8; ++u) {
      if (u < 4 ? v0 : v1) {
        const int d = dd[u];
        const int bk = d >> BUCK_SHIFT;
        const int p = atomicAdd(&cur[bk], 1);
        int idx = base_s[bk] + p;
        if (idx >= SLABCAP) idx = SLABCAP - 1;   // statistically never
        slab[(size_t)bk * SLABCAP + idx] =
            ((unsigned int)ss[u] << BUCK_SHIFT) | (unsigned int)(d & (BUCK_NODES - 1));
      }
    }
    return;
  }

  // ---------------- gemm path: 64 rows x 128 cols, 4 waves x 16 rows -------
  _Float16* xt = (_Float16*)smem;            // 16 KB, swizzled [row][k]
  _Float16* wt = (_Float16*)(smem + 16384);  // 32 KB, swizzled [n][k]
  const int row0 = blockIdx.x * 64;
  const int lane = tid & 63;
  const int wv = tid >> 6;
  const int ql = lane & 15;
  const int quad = lane >> 4;

  {
    const half8* s = (const half8*)wt_g;
    half8* d = (half8*)wt;
#pragma unroll
    for (int i = 0; i < 8; ++i) d[tid + i * 256] = s[tid + i * 256];
  }
  {
    const int r = tid >> 2;
    const int grow = row0 + r;
    const int c0 = (tid & 3) * 32;
#pragma unroll
    for (int cc = 0; cc < 32; cc += 8) {
      const int c = c0 + cc;
      float4 v0 = make_float4(0.f, 0.f, 0.f, 0.f);
      float4 v1 = make_float4(0.f, 0.f, 0.f, 0.f);
      if (grow < n) {
        const float* sp = &x[(size_t)grow * DIM + c];
        v0 = *(const float4*)(sp);
        v1 = *(const float4*)(sp + 4);
      }
      half8 h;
      h[0] = (_Float16)v0.x; h[1] = (_Float16)v0.y;
      h[2] = (_Float16)v0.z; h[3] = (_Float16)v0.w;
      h[4] = (_Float16)v1.x; h[5] = (_Float16)v1.y;
      h[6] = (_Float16)v1.z; h[7] = (_Float16)v1.w;
      const int chunk = c >> 3;
      *(half8*)&xt[r * 128 + ((chunk ^ (r & 15)) << 3)] = h;
    }
  }
  __syncthreads();

  floatx4 acc[8];
#pragma unroll
  for (int t = 0; t < 8; ++t) acc[t] = (floatx4){0.f, 0.f, 0.f, 0.f};

  const int arow = wv * 16 + ql;
  half8 af[4];
#pragma unroll
  for (int s = 0; s < 4; ++s) {
    const int chunk = s * 4 + quad;
    af[s] = *(half8*)&xt[arow * 128 + ((chunk ^ ql) << 3)];
  }
#pragma unroll
  for (int t = 0; t < 8; ++t) {
    const int brow = t * 16 + ql;
#pragma unroll
    for (int s = 0; s < 4; ++s) {
      const int chunk = s * 4 + quad;
      const half8 bf = *(half8*)&wt[brow * 128 + ((chunk ^ ql) << 3)];
      acc[t] = __builtin_amdgcn_mfma_f32_16x16x32_f16(af[s], bf, acc[t], 0, 0, 0);
    }
  }

  {
    float al8[8], ar8[8];
#pragma unroll
    for (int t = 0; t < 8; ++t) {
      al8[t] = attn_l[t * 16 + ql];
      ar8[t] = attn_r[t * 16 + ql];
    }
    float pl[4] = {0.f, 0.f, 0.f, 0.f};
    float pr[4] = {0.f, 0.f, 0.f, 0.f};
#pragma unroll
    for (int t = 0; t < 8; ++t)
#pragma unroll
      for (int r = 0; r < 4; ++r) {
        pl[r] = fmaf(acc[t][r], al8[t], pl[r]);
        pr[r] = fmaf(acc[t][r], ar8[t], pr[r]);
      }
#pragma unroll
    for (int o = 1; o < 16; o <<= 1)
#pragma unroll
      for (int r = 0; r < 4; ++r) {
        pl[r] += __shfl_xor(pl[r], o, 64);
        pr[r] += __shfl_xor(pr[r], o, 64);
      }
    if (ql == 0) {
#pragma unroll
      for (int r = 0; r < 4; ++r) {
        const int grow = row0 + wv * 16 + quad * 4 + r;
        if (grow < n) { el[grow] = pl[r]; er[grow] = pr[r]; }
      }
    }
  }

#pragma unroll
  for (int t = 0; t < 8; ++t)
#pragma unroll
    for (int r = 0; r < 4; ++r)
      xt[(wv * 16 + quad * 4 + r) * 128 + t * 16 + ql] = (_Float16)acc[t][r];
  __syncthreads();
  {
    const int r = tid >> 2;
    const int grow = row0 + r;
    if (grow < n) {
      const int c0 = (tid & 3) * 32;
#pragma unroll
      for (int cc = 0; cc < 32; cc += 8) {
        const half8 h = *(half8*)&xt[r * 128 + c0 + cc];
        feat16[(size_t)grow * 16 + ((c0 + cc) >> 3)] = h;
      }
    }
  }
}

// ---------------------------------------------------------------------------
// K2: aggregation.  One block per 32-node bucket (1563 blocks).  LDS sort by
// exact dst, single fused softmax pass (no max-subtraction), gather x4.
// Epilogue stores h as fp8 e4m3 (score is the only consumer; halves its
// random-gather bytes).
// ---------------------------------------------------------------------------
__global__ __launch_bounds__(256) void aggregate_kernel(
    const half8* __restrict__ feat16, const float* __restrict__ el,
    const float* __restrict__ er,
    const unsigned int* __restrict__ slab, const int* __restrict__ cursors,
    const float* __restrict__ bias, unsigned char* __restrict__ h8)
{
  __shared__ unsigned int csr[SLABCAP];
  __shared__ int cnt_l[BUCK_NODES];
  __shared__ int start_l[BUCK_NODES];
  __shared__ int cur_l[BUCK_NODES];
  const int b = blockIdx.x;
  const int tid = threadIdx.x;
  const int cnt = min(cursors[b], SLABCAP);
  const unsigned int* sb = slab + (size_t)b * SLABCAP;
  const int node0 = b << BUCK_SHIFT;

  if (tid < BUCK_NODES) cnt_l[tid] = 0;
  __syncthreads();
  for (int i = tid; i < cnt; i += 256)
    atomicAdd(&cnt_l[sb[i] & (BUCK_NODES - 1)], 1);
  __syncthreads();
  if (tid < 64) {
    const int v = (tid < BUCK_NODES) ? cnt_l[tid] : 0;
    int inc = v;
#pragma unroll
    for (int d = 1; d < 32; d <<= 1) {
      const int t = __shfl_up(inc, d, 64);
      if (tid >= d) inc += t;
    }
    if (tid < BUCK_NODES) { start_l[tid] = inc - v; cur_l[tid] = 0; }
  }
  __syncthreads();
  for (int i = tid; i < cnt; i += 256) {
    const unsigned int r = sb[i];
    const int p = atomicAdd(&cur_l[r & (BUCK_NODES - 1)], 1);
    csr[start_l[r & (BUCK_NODES - 1)] + p] = r;
  }
  __syncthreads();

  const int lane = tid & 63;
  const int ql = lane & 15;
  const int qb = lane & 48;
  const int qid = (tid >> 6) * 4 + (lane >> 4);
  const float4 b0 = *(const float4*)&bias[ql * 8];
  const float4 b1 = *(const float4*)&bias[ql * 8 + 4];
  const float bb[8] = {b0.x, b0.y, b0.z, b0.w, b1.x, b1.y, b1.z, b1.w};

  for (int nl = qid; nl < BUCK_NODES; nl += 16) {
    const int node = node0 + nl;
    if (node >= N_NODES) break;
    const int beg = start_l[nl];
    const int c = cnt_l[nl];
    const float ern = er[node];

    float sp = 0.f;
    float acc[8];
#pragma unroll
    for (int k = 0; k < 8; ++k) acc[k] = 0.f;

    for (int t0 = 0; t0 < c; t0 += 16) {
      const int t = t0 + ql;
      const unsigned int r = csr[beg + ((t < c) ? t : (c - 1))];
      const int sid = (int)(r >> BUCK_SHIFT);
      float w = 0.f;
      if (t < c) {
        const float v = el[sid] + ern;
        const float e = (v > 0.f) ? v : NEG_SLOPE * v;
        w = __expf(e);
      }
      sp += w;
      const int nb = min(16, c - t0);
      int j = 0;
      for (; j + 4 <= nb; j += 4) {
        float wv[4]; int sv[4]; half8 fv[4];
#pragma unroll
        for (int u = 0; u < 4; ++u) {
          wv[u] = __shfl(w, qb + j + u, 64);
          sv[u] = __shfl(sid, qb + j + u, 64);
        }
#pragma unroll
        for (int u = 0; u < 4; ++u) fv[u] = feat16[(size_t)sv[u] * 16 + ql];
#pragma unroll
        for (int u = 0; u < 4; ++u)
#pragma unroll
          for (int k = 0; k < 8; ++k)
            acc[k] = fmaf(wv[u], (float)fv[u][k], acc[k]);
      }
      for (; j < nb; ++j) {
        const float wj = __shfl(w, qb + j, 64);
        const int sj = __shfl(sid, qb + j, 64);
        const half8 f = feat16[(size_t)sj * 16 + ql];
#pragma unroll
        for (int k = 0; k < 8; ++k) acc[k] = fmaf(wj, (float)f[k], acc[k]);
      }
    }

#pragma unroll
    for (int o = 1; o < 16; o <<= 1) sp += __shfl_xor(sp, o, 64);

    const float inv = (c > 0) ? 1.f / sp : 0.f;
    union { unsigned char b[8]; uint2 u; } o;
#pragma unroll
    for (int k = 0; k < 8; ++k)
      o.b[k] = f_to_fp8(fmaxf(acc[k] * inv + bb[k], 0.f));
    *(uint2*)&h8[(size_t)node * 128 + ql * 8] = o.u;
  }
}

// ---------------------------------------------------------------------------
// K3: scores.  4 pairs per quarter-wave (16 pairs/wave); fp8 rows, 8 B/lane
// loads (128 B per row per quarter-wave), hardware fp8->f32 converts.
// ---------------------------------------------------------------------------
__global__ __launch_bounds__(256) void score_kernel(
    const unsigned char* __restrict__ h8,
    const int* __restrict__ pos_src, const int* __restrict__ pos_dst,
    const int* __restrict__ neg_src, const int* __restrict__ neg_dst,
    float* __restrict__ out, int ntot)
{
  const int wid = (int)((blockIdx.x * blockDim.x + threadIdx.x) >> 6);
  const int lane = threadIdx.x & 63;
  const int q = lane >> 4;
  const int ql = lane & 15;
  const int base = (wid * 4 + q) * 4;

  int av[4], bv[4];
#pragma unroll
  for (int u = 0; u < 4; ++u) {
    const int p = base + u;
    int a = 0, b = 0;
    if (p < N_POS)      { a = pos_src[p]; b = pos_dst[p]; }
    else if (p < ntot)  { a = neg_src[p - N_POS]; b = neg_dst[p - N_POS]; }
    av[u] = a; bv[u] = b;
  }
  uint2 ha[4], hb[4];
#pragma unroll
  for (int u = 0; u < 4; ++u) {
    ha[u] = *(const uint2*)&h8[(size_t)av[u] * 128 + ql * 8];
    hb[u] = *(const uint2*)&h8[(size_t)bv[u] * 128 + ql * 8];
  }
  float sum[4];
#pragma unroll
  for (int u = 0; u < 4; ++u) {
    union { uint2 u2; unsigned char b[8]; } xa, xb;
    xa.u2 = ha[u]; xb.u2 = hb[u];
    float s = 0.f;
#pragma unroll
    for (int k = 0; k < 8; ++k)
      s = fmaf(fp8_to_f(xa.b[k]), fp8_to_f(xb.b[k]), s);
#pragma unroll
    for (int o = 8; o > 0; o >>= 1) s += __shfl_xor(s, o, 64);
    sum[u] = s;
  }
  if (ql == 0) {
#pragma unroll
    for (int u = 0; u < 4; ++u) {
      const int p = base + u;
      if (p < ntot) out[p] = sum[u];
    }
  }
}

// ---------------------------------------------------------------------------
extern "C" void kernel_launch(void* const* d_in, const int* in_sizes, int n_in,
                              void* d_out, int out_size, void* d_ws, size_t ws_size,
                              hipStream_t stream) {
  const float* x      = (const float*)d_in[0];
  const float* W      = (const float*)d_in[1];
  const float* attn_l = (const float*)d_in[2];
  const float* attn_r = (const float*)d_in[3];
  const float* bias   = (const float*)d_in[4];
  const int* src      = (const int*)d_in[5];
  const int* dst      = (const int*)d_in[6];
  const int* pos_src  = (const int*)d_in[7];
  const int* pos_dst  = (const int*)d_in[8];
  const int* neg_src  = (const int*)d_in[9];
  const int* neg_dst  = (const int*)d_in[10];
  float* out = (float*)d_out;

  char* ws = (char*)d_ws;
  const size_t F16B   = (size_t)N_NODES * DIM * sizeof(_Float16);       // 12.8 MB
  const size_t H8B    = (size_t)N_NODES * DIM;                          // 6.4 MB
  const size_t SLAB_B = (size_t)NBUCK * SLABCAP * sizeof(unsigned int); // 4.8 MB
  half8* feat16      = (half8*)(ws);
  unsigned char* h8  = (unsigned char*)(ws + F16B);
  float* el          = (float*)(ws + F16B + H8B);
  float* er          = (float*)(ws + F16B + H8B + 200000);
  int*   cursors     = (int*)  (ws + F16B + H8B + 400000);
  unsigned int* slab = (unsigned int*)(ws + F16B + H8B + 406656);
  _Float16* wt_g     = (_Float16*)(ws + F16B + H8B + 406656 + SLAB_B);

  prep_kernel<<<4, 256, 0, stream>>>(W, wt_g, cursors);
  fused_gemm_bin<<<NB_GEMM + NB_BIN, 256, 0, stream>>>(
      x, wt_g, attn_l, attn_r, (const int4*)src, (const int4*)dst,
      feat16, el, er, slab, cursors, N_NODES);
  aggregate_kernel<<<NBUCK, 256, 0, stream>>>(
      feat16, el, er, slab, cursors, bias, h8);
  score_kernel<<<((N_POS + N_NEG + 15) / 16 + 3) / 4, 256, 0, stream>>>(
      h8, pos_src, pos_dst, neg_src, neg_dst, out, N_POS + N_NEG);
}